// Round 1
// baseline (8800.397 us; speedup 1.0000x reference)
//
#include <hip/hip_runtime.h>
#include <math.h>

// 3-layer LSTM (H=64, T=512, B=2048, Din=16) fused persistent kernel.
// Each block owns CB=8 batch rows and runs the whole time loop for all 3
// layers, pipelined: layer l processes timestep (it - l). Weights are held in
// registers (one gate row per thread: 256 rows/layer x 3 layers = 768 threads).
// h is exchanged via double-buffered LDS; c lives in registers of the
// elementwise-owning thread. Two block barriers per iteration.

#define TSTEPS 512
#define HID    64
#define G4     256   // 4*HID
#define DIN0   16
#define CB     8     // batch rows per block
#define NTHREADS 768
#define BATCH  2048

__device__ __forceinline__ float sigm(float z) {
    return 1.0f / (1.0f + __expf(-z));
}
__device__ __forceinline__ float tanh_fast(float z) {
    z = fminf(15.0f, fmaxf(-15.0f, z));
    const float e = __expf(2.0f * z);
    return (e - 1.0f) / (e + 1.0f);
}

__global__ __launch_bounds__(NTHREADS) void lstm3_fused(
    const float* __restrict__ x,      // [B, T, 16]
    const float* __restrict__ Wih0,   // [256,16]
    const float* __restrict__ Whh0,   // [256,64]
    const float* __restrict__ bih0,   // [256]
    const float* __restrict__ bhh0,   // [256]
    const float* __restrict__ Wih1,   // [256,64]
    const float* __restrict__ Whh1,   // [256,64]
    const float* __restrict__ bih1,
    const float* __restrict__ bhh1,
    const float* __restrict__ Wih2,   // [256,64]
    const float* __restrict__ Whh2,   // [256,64]
    const float* __restrict__ bih2,
    const float* __restrict__ bhh2,
    const float* __restrict__ Wout,   // [7,64]
    const float* __restrict__ bout,   // [7]
    float* __restrict__ out)          // [B,7]
{
    __shared__ __attribute__((aligned(16))) float xs[2][CB][DIN0];
    __shared__ __attribute__((aligned(16))) float h0b[2][CB][HID];
    __shared__ __attribute__((aligned(16))) float h1b[2][CB][HID];
    __shared__ __attribute__((aligned(16))) float h2b[2][CB][HID];
    __shared__ __attribute__((aligned(16))) float gates[3][CB][G4];

    const int tid = threadIdx.x;
    const int grp = tid >> 8;     // layer group 0..2
    const int r   = tid & 255;    // gate row within layer
    const int b0  = blockIdx.x * CB;

    // ---- load this thread's gate-row weights into registers ----
    float wih[HID];
    float whh[HID];
    float bias;
    if (grp == 0) {
        #pragma unroll
        for (int k = 0; k < DIN0; ++k) wih[k] = Wih0[r * DIN0 + k];
        #pragma unroll
        for (int k = DIN0; k < HID; ++k) wih[k] = 0.0f;
        #pragma unroll
        for (int k = 0; k < HID; ++k) whh[k] = Whh0[r * HID + k];
        bias = bih0[r] + bhh0[r];
    } else if (grp == 1) {
        #pragma unroll
        for (int k = 0; k < HID; ++k) wih[k] = Wih1[r * HID + k];
        #pragma unroll
        for (int k = 0; k < HID; ++k) whh[k] = Whh1[r * HID + k];
        bias = bih1[r] + bhh1[r];
    } else {
        #pragma unroll
        for (int k = 0; k < HID; ++k) wih[k] = Wih2[r * HID + k];
        #pragma unroll
        for (int k = 0; k < HID; ++k) whh[k] = Whh2[r * HID + k];
        bias = bih2[r] + bhh2[r];
    }

    // ---- zero h double-buffers (both slots), stage x[t=0] ----
    for (int i = tid; i < 2 * CB * HID; i += NTHREADS) {
        (&h0b[0][0][0])[i] = 0.0f;
        (&h1b[0][0][0])[i] = 0.0f;
        (&h2b[0][0][0])[i] = 0.0f;
    }
    if (tid < 128) {
        xs[0][tid >> 4][tid & 15] =
            x[(b0 + (tid >> 4)) * (TSTEPS * DIN0) + (tid & 15)];
    }

    float cst0 = 0.0f, cst1 = 0.0f;   // c state: 2 (batch,unit) cells per thread

    __syncthreads();

    for (int it = 0; it < TSTEPS + 2; ++it) {
        const int t = it - grp;                  // this group's timestep
        const bool act = (t >= 0) && (t < TSTEPS);
        const int ps = (it + 1) & 1;             // previous h slot = (it-1)&1

        // ================= Phase A: gate pre-activations =================
        if (act) {
            float acc[CB];
            #pragma unroll
            for (int b = 0; b < CB; ++b) acc[b] = bias;

            if (grp == 0) {
                const float* src = &xs[t & 1][0][0];
                #pragma unroll
                for (int k4 = 0; k4 < DIN0 / 4; ++k4) {
                    #pragma unroll
                    for (int b = 0; b < CB; ++b) {
                        const float4 a = *(const float4*)(src + b * DIN0 + k4 * 4);
                        acc[b] = fmaf(a.x, wih[k4 * 4 + 0], acc[b]);
                        acc[b] = fmaf(a.y, wih[k4 * 4 + 1], acc[b]);
                        acc[b] = fmaf(a.z, wih[k4 * 4 + 2], acc[b]);
                        acc[b] = fmaf(a.w, wih[k4 * 4 + 3], acc[b]);
                    }
                }
            } else {
                const float* src = (grp == 1) ? &h0b[ps][0][0] : &h1b[ps][0][0];
                #pragma unroll
                for (int k4 = 0; k4 < HID / 4; ++k4) {
                    #pragma unroll
                    for (int b = 0; b < CB; ++b) {
                        const float4 a = *(const float4*)(src + b * HID + k4 * 4);
                        acc[b] = fmaf(a.x, wih[k4 * 4 + 0], acc[b]);
                        acc[b] = fmaf(a.y, wih[k4 * 4 + 1], acc[b]);
                        acc[b] = fmaf(a.z, wih[k4 * 4 + 2], acc[b]);
                        acc[b] = fmaf(a.w, wih[k4 * 4 + 3], acc[b]);
                    }
                }
            }
            {
                const float* hs = (grp == 0) ? &h0b[ps][0][0]
                                : (grp == 1) ? &h1b[ps][0][0]
                                             : &h2b[ps][0][0];
                #pragma unroll
                for (int k4 = 0; k4 < HID / 4; ++k4) {
                    #pragma unroll
                    for (int b = 0; b < CB; ++b) {
                        const float4 a = *(const float4*)(hs + b * HID + k4 * 4);
                        acc[b] = fmaf(a.x, whh[k4 * 4 + 0], acc[b]);
                        acc[b] = fmaf(a.y, whh[k4 * 4 + 1], acc[b]);
                        acc[b] = fmaf(a.z, whh[k4 * 4 + 2], acc[b]);
                        acc[b] = fmaf(a.w, whh[k4 * 4 + 3], acc[b]);
                    }
                }
            }
            float* gdst = &gates[grp][0][0];
            #pragma unroll
            for (int b = 0; b < CB; ++b) gdst[b * G4 + r] = acc[b];
        }
        __syncthreads();

        // ================= Phase B: elementwise update ===================
        if (act) {
            const int u  = r & 63;
            const int bb = r >> 6;     // handles batch rows bb and bb+4
            float* hdst = (grp == 0) ? &h0b[it & 1][0][0]
                        : (grp == 1) ? &h1b[it & 1][0][0]
                                     : &h2b[it & 1][0][0];
            const float* gsrc = &gates[grp][0][0];
            {
                const int b = bb;
                const float gi = gsrc[b * G4 + u];
                const float gf = gsrc[b * G4 + 64 + u];
                const float gg = gsrc[b * G4 + 128 + u];
                const float go = gsrc[b * G4 + 192 + u];
                const float c  = sigm(gf) * cst0 + sigm(gi) * tanh_fast(gg);
                cst0 = c;
                hdst[b * HID + u] = sigm(go) * tanh_fast(c);
            }
            {
                const int b = bb + 4;
                const float gi = gsrc[b * G4 + u];
                const float gf = gsrc[b * G4 + 64 + u];
                const float gg = gsrc[b * G4 + 128 + u];
                const float go = gsrc[b * G4 + 192 + u];
                const float c  = sigm(gf) * cst1 + sigm(gi) * tanh_fast(gg);
                cst1 = c;
                hdst[b * HID + u] = sigm(go) * tanh_fast(c);
            }
        }
        // stage next x tile (group 0's next timestep), hidden under phase B
        if (grp == 0 && r < 128 && (it + 1) < TSTEPS) {
            xs[(it + 1) & 1][r >> 4][r & 15] =
                x[(b0 + (r >> 4)) * (TSTEPS * DIN0) + (it + 1) * DIN0 + (r & 15)];
        }
        __syncthreads();
    }

    // ================= head: out = h2[T-1] @ Wout.T + bout ==============
    if (grp == 2 && r < 7 * CB) {
        const int b = r / 7;
        const int o = r % 7;
        float a2 = bout[o];
        #pragma unroll
        for (int k = 0; k < HID; ++k)
            a2 = fmaf(h2b[(TSTEPS + 1) & 1][b][k], Wout[o * HID + k], a2);
        out[(b0 + b) * 7 + o] = a2;
    }
}

extern "C" void kernel_launch(void* const* d_in, const int* in_sizes, int n_in,
                              void* d_out, int out_size, void* d_ws, size_t ws_size,
                              hipStream_t stream) {
    const float* x    = (const float*)d_in[0];
    const float* Wih0 = (const float*)d_in[1];
    const float* Whh0 = (const float*)d_in[2];
    const float* bih0 = (const float*)d_in[3];
    const float* bhh0 = (const float*)d_in[4];
    const float* Wih1 = (const float*)d_in[5];
    const float* Whh1 = (const float*)d_in[6];
    const float* bih1 = (const float*)d_in[7];
    const float* bhh1 = (const float*)d_in[8];
    const float* Wih2 = (const float*)d_in[9];
    const float* Whh2 = (const float*)d_in[10];
    const float* bih2 = (const float*)d_in[11];
    const float* bhh2 = (const float*)d_in[12];
    const float* Wout = (const float*)d_in[13];
    const float* bout = (const float*)d_in[14];
    float* out = (float*)d_out;

    lstm3_fused<<<dim3(BATCH / CB), dim3(NTHREADS), 0, stream>>>(
        x, Wih0, Whh0, bih0, bhh0,
        Wih1, Whh1, bih1, bhh1,
        Wih2, Whh2, bih2, bhh2,
        Wout, bout, out);
}

// Round 2
// 8788.638 us; speedup vs baseline: 1.0013x; 1.0013x over previous
//
#include <hip/hip_runtime.h>
#include <math.h>

// 3-layer LSTM (H=64, T=512, B=2048, Din=16) fused persistent kernel.
// Each block owns CB=8 batch rows and runs the whole time loop for all 3
// layers, pipelined: layer l processes timestep (it - l). Weights are held in
// registers (one gate row per thread: 256 rows/layer x 3 layers = 768 threads).
// R2 fix: __launch_bounds__(768,3) raises the VGPR cap (was spilling at 84
// VGPRs -> 18.6 GB of scratch HBM traffic); weights held as float4[16] with
// compile-time indices only, so SROA promotes them to registers.

#define TSTEPS 512
#define HID    64
#define G4     256   // 4*HID
#define DIN0   16
#define CB     8     // batch rows per block
#define NTHREADS 768
#define BATCH  2048

__device__ __forceinline__ float sigm(float z) {
    return 1.0f / (1.0f + __expf(-z));
}
__device__ __forceinline__ float tanh_fast(float z) {
    z = fminf(15.0f, fmaxf(-15.0f, z));
    const float e = __expf(2.0f * z);
    return (e - 1.0f) / (e + 1.0f);
}

__global__ __launch_bounds__(NTHREADS, 3) void lstm3_fused(
    const float* __restrict__ x,      // [B, T, 16]
    const float* __restrict__ Wih0,   // [256,16]
    const float* __restrict__ Whh0,   // [256,64]
    const float* __restrict__ bih0,   // [256]
    const float* __restrict__ bhh0,   // [256]
    const float* __restrict__ Wih1,   // [256,64]
    const float* __restrict__ Whh1,   // [256,64]
    const float* __restrict__ bih1,
    const float* __restrict__ bhh1,
    const float* __restrict__ Wih2,   // [256,64]
    const float* __restrict__ Whh2,   // [256,64]
    const float* __restrict__ bih2,
    const float* __restrict__ bhh2,
    const float* __restrict__ Wout,   // [7,64]
    const float* __restrict__ bout,   // [7]
    float* __restrict__ out)          // [B,7]
{
    __shared__ __attribute__((aligned(16))) float xs[2][CB][DIN0];
    __shared__ __attribute__((aligned(16))) float h0b[2][CB][HID];
    __shared__ __attribute__((aligned(16))) float h1b[2][CB][HID];
    __shared__ __attribute__((aligned(16))) float h2b[2][CB][HID];
    __shared__ __attribute__((aligned(16))) float gates[3][CB][G4];

    const int tid = threadIdx.x;
    const int grp = tid >> 8;     // layer group 0..2
    const int r   = tid & 255;    // gate row within layer
    const int b0  = blockIdx.x * CB;

    // ---- load this thread's gate-row weights into registers (float4,
    //      compile-time indices only -> SROA to VGPRs) ----
    float4 wih4[HID / 4];
    float4 whh4[HID / 4];
    float bias;
    if (grp == 0) {
        const float4* wi = (const float4*)(Wih0 + r * DIN0);
        #pragma unroll
        for (int k = 0; k < DIN0 / 4; ++k) wih4[k] = wi[k];
        #pragma unroll
        for (int k = DIN0 / 4; k < HID / 4; ++k)
            wih4[k] = make_float4(0.f, 0.f, 0.f, 0.f);
        const float4* wh = (const float4*)(Whh0 + r * HID);
        #pragma unroll
        for (int k = 0; k < HID / 4; ++k) whh4[k] = wh[k];
        bias = bih0[r] + bhh0[r];
    } else if (grp == 1) {
        const float4* wi = (const float4*)(Wih1 + r * HID);
        const float4* wh = (const float4*)(Whh1 + r * HID);
        #pragma unroll
        for (int k = 0; k < HID / 4; ++k) { wih4[k] = wi[k]; whh4[k] = wh[k]; }
        bias = bih1[r] + bhh1[r];
    } else {
        const float4* wi = (const float4*)(Wih2 + r * HID);
        const float4* wh = (const float4*)(Whh2 + r * HID);
        #pragma unroll
        for (int k = 0; k < HID / 4; ++k) { wih4[k] = wi[k]; whh4[k] = wh[k]; }
        bias = bih2[r] + bhh2[r];
    }

    // ---- zero h double-buffers (both slots), stage x[t=0] ----
    for (int i = tid; i < 2 * CB * HID; i += NTHREADS) {
        (&h0b[0][0][0])[i] = 0.0f;
        (&h1b[0][0][0])[i] = 0.0f;
        (&h2b[0][0][0])[i] = 0.0f;
    }
    if (tid < 128) {
        xs[0][tid >> 4][tid & 15] =
            x[(b0 + (tid >> 4)) * (TSTEPS * DIN0) + (tid & 15)];
    }

    float cst0 = 0.0f, cst1 = 0.0f;   // c state: 2 (batch,unit) cells per thread

    __syncthreads();

    for (int it = 0; it < TSTEPS + 2; ++it) {
        const int t = it - grp;                  // this group's timestep
        const bool act = (t >= 0) && (t < TSTEPS);
        const int ps = (it + 1) & 1;             // previous h slot = (it-1)&1

        // ================= Phase A: gate pre-activations =================
        if (act) {
            float acc[CB];
            #pragma unroll
            for (int b = 0; b < CB; ++b) acc[b] = bias;

            if (grp == 0) {
                const float* src = &xs[t & 1][0][0];
                #pragma unroll
                for (int k4 = 0; k4 < DIN0 / 4; ++k4) {
                    #pragma unroll
                    for (int b = 0; b < CB; ++b) {
                        const float4 a = *(const float4*)(src + b * DIN0 + k4 * 4);
                        acc[b] = fmaf(a.x, wih4[k4].x, acc[b]);
                        acc[b] = fmaf(a.y, wih4[k4].y, acc[b]);
                        acc[b] = fmaf(a.z, wih4[k4].z, acc[b]);
                        acc[b] = fmaf(a.w, wih4[k4].w, acc[b]);
                    }
                }
            } else {
                const float* src = (grp == 1) ? &h0b[ps][0][0] : &h1b[ps][0][0];
                #pragma unroll
                for (int k4 = 0; k4 < HID / 4; ++k4) {
                    #pragma unroll
                    for (int b = 0; b < CB; ++b) {
                        const float4 a = *(const float4*)(src + b * HID + k4 * 4);
                        acc[b] = fmaf(a.x, wih4[k4].x, acc[b]);
                        acc[b] = fmaf(a.y, wih4[k4].y, acc[b]);
                        acc[b] = fmaf(a.z, wih4[k4].z, acc[b]);
                        acc[b] = fmaf(a.w, wih4[k4].w, acc[b]);
                    }
                }
            }
            {
                const float* hs = (grp == 0) ? &h0b[ps][0][0]
                                : (grp == 1) ? &h1b[ps][0][0]
                                             : &h2b[ps][0][0];
                #pragma unroll
                for (int k4 = 0; k4 < HID / 4; ++k4) {
                    #pragma unroll
                    for (int b = 0; b < CB; ++b) {
                        const float4 a = *(const float4*)(hs + b * HID + k4 * 4);
                        acc[b] = fmaf(a.x, whh4[k4].x, acc[b]);
                        acc[b] = fmaf(a.y, whh4[k4].y, acc[b]);
                        acc[b] = fmaf(a.z, whh4[k4].z, acc[b]);
                        acc[b] = fmaf(a.w, whh4[k4].w, acc[b]);
                    }
                }
            }
            float* gdst = &gates[grp][0][0];
            #pragma unroll
            for (int b = 0; b < CB; ++b) gdst[b * G4 + r] = acc[b];
        }
        __syncthreads();

        // ================= Phase B: elementwise update ===================
        if (act) {
            const int u  = r & 63;
            const int bb = r >> 6;     // handles batch rows bb and bb+4
            float* hdst = (grp == 0) ? &h0b[it & 1][0][0]
                        : (grp == 1) ? &h1b[it & 1][0][0]
                                     : &h2b[it & 1][0][0];
            const float* gsrc = &gates[grp][0][0];
            {
                const int b = bb;
                const float gi = gsrc[b * G4 + u];
                const float gf = gsrc[b * G4 + 64 + u];
                const float gg = gsrc[b * G4 + 128 + u];
                const float go = gsrc[b * G4 + 192 + u];
                const float c  = sigm(gf) * cst0 + sigm(gi) * tanh_fast(gg);
                cst0 = c;
                hdst[b * HID + u] = sigm(go) * tanh_fast(c);
            }
            {
                const int b = bb + 4;
                const float gi = gsrc[b * G4 + u];
                const float gf = gsrc[b * G4 + 64 + u];
                const float gg = gsrc[b * G4 + 128 + u];
                const float go = gsrc[b * G4 + 192 + u];
                const float c  = sigm(gf) * cst1 + sigm(gi) * tanh_fast(gg);
                cst1 = c;
                hdst[b * HID + u] = sigm(go) * tanh_fast(c);
            }
        }
        // stage next x tile (group 0's next timestep), hidden under phase B
        if (grp == 0 && r < 128 && (it + 1) < TSTEPS) {
            xs[(it + 1) & 1][r >> 4][r & 15] =
                x[(b0 + (r >> 4)) * (TSTEPS * DIN0) + (it + 1) * DIN0 + (r & 15)];
        }
        __syncthreads();
    }

    // ================= head: out = h2[T-1] @ Wout.T + bout ==============
    if (grp == 2 && r < 7 * CB) {
        const int b = r / 7;
        const int o = r % 7;
        float a2 = bout[o];
        #pragma unroll
        for (int k = 0; k < HID; ++k)
            a2 = fmaf(h2b[(TSTEPS + 1) & 1][b][k], Wout[o * HID + k], a2);
        out[(b0 + b) * 7 + o] = a2;
    }
}

extern "C" void kernel_launch(void* const* d_in, const int* in_sizes, int n_in,
                              void* d_out, int out_size, void* d_ws, size_t ws_size,
                              hipStream_t stream) {
    const float* x    = (const float*)d_in[0];
    const float* Wih0 = (const float*)d_in[1];
    const float* Whh0 = (const float*)d_in[2];
    const float* bih0 = (const float*)d_in[3];
    const float* bhh0 = (const float*)d_in[4];
    const float* Wih1 = (const float*)d_in[5];
    const float* Whh1 = (const float*)d_in[6];
    const float* bih1 = (const float*)d_in[7];
    const float* bhh1 = (const float*)d_in[8];
    const float* Wih2 = (const float*)d_in[9];
    const float* Whh2 = (const float*)d_in[10];
    const float* bih2 = (const float*)d_in[11];
    const float* bhh2 = (const float*)d_in[12];
    const float* Wout = (const float*)d_in[13];
    const float* bout = (const float*)d_in[14];
    float* out = (float*)d_out;

    lstm3_fused<<<dim3(BATCH / CB), dim3(NTHREADS), 0, stream>>>(
        x, Wih0, Whh0, bih0, bhh0,
        Wih1, Whh1, bih1, bhh1,
        Wih2, Whh2, bih2, bhh2,
        Wout, bout, out);
}